// Round 19
// baseline (136.477 us; speedup 1.0000x reference)
//
#include <hip/hip_runtime.h>

#define T_LEN 512
#define B_SZ  256
#define N_ST  128

#if defined(__has_builtin)
# if __has_builtin(__builtin_amdgcn_fdot2_f32_bf16)
#  define HAVE_DOT2 1
# endif
#endif
#ifndef HAVE_DOT2
# define HAVE_DOT2 0
#endif

typedef unsigned int uint32;
typedef __bf16 bf16x2 __attribute__((ext_vector_type(2)));
typedef float f2v __attribute__((ext_vector_type(2)));
typedef uint4 __attribute__((may_alias)) uint4a;   // alias-safe LDS vector read

__device__ __forceinline__ uint32 bf16rn(float f) {
    uint32 u = __builtin_bit_cast(uint32, f);
    u += 0x7fffu + ((u >> 16) & 1u);
    return u >> 16;
}
__device__ __forceinline__ uint32 pack2(float lo, float hi) {
    return bf16rn(lo) | (bf16rn(hi) << 16);
}
__device__ __forceinline__ uint32 cvtpk(float lo, float hi) {
    uint32 r;
    asm("v_cvt_pk_bf16_f32 %0, %1, %2" : "=v"(r) : "v"(lo), "v"(hi));
    return r;
}
__device__ __forceinline__ float readlane0(float v) {
    return __builtin_bit_cast(float, (uint32)__builtin_amdgcn_readlane(__builtin_bit_cast(int, v), 0));
}
__device__ __forceinline__ float dot2b(uint32 a, uint32 b, float c) {
#if HAVE_DOT2
    return __builtin_amdgcn_fdot2_f32_bf16(__builtin_bit_cast(bf16x2, a),
                                           __builtin_bit_cast(bf16x2, b), c, false);
#else
    float alo = __builtin_bit_cast(float, a << 16);
    float ahi = __builtin_bit_cast(float, a & 0xffff0000u);
    float blo = __builtin_bit_cast(float, b << 16);
    float bhi = __builtin_bit_cast(float, b & 0xffff0000u);
    return fmaf(ahi, bhi, fmaf(alo, blo, c));
#endif
}

// Per-wave length computation: 64 lanes x 8 mask entries for batch b.
__device__ __forceinline__ int wave_len(const unsigned char* __restrict__ mask_raw, int b, int l) {
    unsigned char b1 = mask_raw[1], b2 = mask_raw[2];
    int mode = (b1 != 0) ? 0 : ((b2 != 0) ? 2 : 1);
    int cnt = 0;
    if (mode == 0) {
        #pragma unroll
        for (int k = 0; k < 8; ++k) cnt += (mask_raw[(l * 8 + k) * B_SZ + b] != 0);
    } else if (mode == 1) {
        const int* mm = (const int*)mask_raw;
        #pragma unroll
        for (int k = 0; k < 8; ++k) cnt += (mm[(l * 8 + k) * B_SZ + b] != 0);
    } else {
        const float* mm = (const float*)mask_raw;
        #pragma unroll
        for (int k = 0; k < 8; ++k) cnt += (mm[(l * 8 + k) * B_SZ + b] != 0.0f);
    }
    #pragma unroll
    for (int off = 1; off < 64; off <<= 1) cnt += __shfl_xor(cnt, off);
    return cnt;
}

// ws layout (floats): [0..255] logZ_b ; [256..511] score_b ; [512] done-counter (uint)

// Fully-fused single-pass CRF: one block per batch, 3 waves.
//   wave0: forward recurrence  a_t = ee_t o (E^T a_{t-1}),  t = 1..m
//   wave1: backward recurrence y_{t-1} = E (ee_t o y_t),    t = len-1..m+1
//   wave2: Viterbi-path score, concurrent with the 256-step loops
// m = min(256, len-1). Recurrence bodies = R14/R18 verbatim (proven, absmax 0).
// Final NLL reduce runs in the LAST block to finish (threadfence + atomic
// counter, device-scope atomic loads bypass per-CU L1 -- G16), removing the
// separate finalize kernel launch.
__global__ void __attribute__((amdgpu_flat_work_group_size(192, 192), amdgpu_waves_per_eu(1, 1)))
crf_fused_kernel(
        const float* __restrict__ emit,
        const unsigned char* __restrict__ mask_raw,
        const int* __restrict__ target,
        const float* __restrict__ trans,
        const float* __restrict__ strans,
        const float* __restrict__ etrans,
        float* __restrict__ logZ_out,
        float* __restrict__ score_out,
        uint32* __restrict__ done_cnt,
        float* __restrict__ out) {
    const int b   = blockIdx.x;
    const int tid = threadIdx.x;      // 0..191
    const int wid = tid >> 6;         // 0 = fwd, 1 = bwd, 2 = score
    const int l   = tid & 63;
    const int c0  = 2 * l, c1 = 2 * l + 1;

    __shared__ alignas(16) uint32 a32[64];   // fwd a-vector, bf16x2 packed
    __shared__ alignas(16) uint32 z32[64];   // bwd ee*y vector, bf16x2 packed
    __shared__ float meetA[N_ST], meetY[N_ST];
    __shared__ float maccSh[2], red2[2];
    __shared__ int lastFlag;

    const int len = wave_len(mask_raw, b, l);    // per-wave, uniform within wave
    const int m = (len - 1 < 256) ? (len - 1) : 256;
    const float* eb = emit + (size_t)b * N_ST;
    const size_t TS2 = (size_t)B_SZ * N_ST / 2;
    const f2v* ebv = (const f2v*)eb;

    if (wid == 0) {
        // ---- forward: E columns c0, c1 packed over i-pairs ----
        uint32 EA[64], EB[64];
        #pragma unroll
        for (int p = 0; p < 64; ++p) {
            EA[p] = pack2(__expf(trans[(2 * p) * N_ST + c0]), __expf(trans[(2 * p + 1) * N_ST + c0]));
            EB[p] = pack2(__expf(trans[(2 * p) * N_ST + c1]), __expf(trans[(2 * p + 1) * N_ST + c1]));
        }
        float aA = __expf(strans[c0] + eb[c0]);
        float aB = __expf(strans[c1] + eb[c1]);
        a32[l] = pack2(aA, aB);
        float Macc = 0.f, inv = 1.0f;
        #define EIDX(T) ((size_t)(((T) <= m) ? (T) : m) * TS2 + l)
        f2v p0 = ebv[EIDX(1)];
        f2v p1 = ebv[EIDX(2)];
        f2v p2 = ebv[EIDX(3)];
        f2v p3 = ebv[EIDX(4)];
        for (int t = 1; t <= m; ++t) {
            const f2v pn = ebv[EIDX(t + 4)];               // prefetch, 4 iters ahead
            const float ee0 = __expf(p0.x), ee1 = __expf(p0.y);
            float A0 = 0, A1 = 0, A2 = 0, A3 = 0, B0 = 0, B1 = 0, B2 = 0, B3 = 0;
            const uint4a* aw = (const uint4a*)a32;
            #pragma unroll
            for (int q = 0; q < 16; ++q) {
                const uint4 w = aw[q];                     // ds_read_b128 broadcast
                A0 = dot2b(w.x, EA[4 * q + 0], A0);  B0 = dot2b(w.x, EB[4 * q + 0], B0);
                A1 = dot2b(w.y, EA[4 * q + 1], A1);  B1 = dot2b(w.y, EB[4 * q + 1], B1);
                A2 = dot2b(w.z, EA[4 * q + 2], A2);  B2 = dot2b(w.z, EB[4 * q + 2], B2);
                A3 = dot2b(w.w, EA[4 * q + 3], A3);  B3 = dot2b(w.w, EB[4 * q + 3], B3);
            }
            const float rA = (A0 + A1) + (A2 + A3);
            const float rB = (B0 + B1) + (B2 + B3);
            Macc -= __logf(inv);                           // bookkeeping (off write path)
            aA = ee0 * rA * inv;                           // delayed uniform normalizer
            aB = ee1 * rB * inv;
            a32[l] = cvtpk(aA, aB);                        // ONE ds_write_b32
            inv = __builtin_amdgcn_rcpf(readlane0(rA));    // scalar path, NOT DS pipe
            p0 = p1; p1 = p2; p2 = p3; p3 = pn;
        }
        #undef EIDX
        meetA[c0] = aA; meetA[c1] = aB;
        if (l == 0) maccSh[0] = Macc;
    } else if (wid == 1) {
        // ---- backward: E rows c0, c1 packed over j-pairs ----
        uint32 RA[64], RB[64];
        #pragma unroll
        for (int p = 0; p < 64; ++p) {
            RA[p] = pack2(__expf(trans[c0 * N_ST + 2 * p]), __expf(trans[c0 * N_ST + 2 * p + 1]));
            RB[p] = pack2(__expf(trans[c1 * N_ST + 2 * p]), __expf(trans[c1 * N_ST + 2 * p + 1]));
        }
        float y0 = __expf(etrans[c0]);                     // y_{len-1} = exp(etrans)
        float y1 = __expf(etrans[c1]);
        float Maccb = 0.f, invb = 1.0f;
        const int t0 = len - 1;
        #define EIDXB(T) ((size_t)(((T) > m) ? (T) : (m + 1)) * TS2 + l)
        f2v p0 = ebv[EIDXB(t0)];
        f2v p1 = ebv[EIDXB(t0 - 1)];
        f2v p2 = ebv[EIDXB(t0 - 2)];
        f2v p3 = ebv[EIDXB(t0 - 3)];
        for (int t = t0; t > m; --t) {
            const f2v pn = ebv[EIDXB(t - 4)];              // prefetch, 4 iters ahead
            const float ee0 = __expf(p0.x), ee1 = __expf(p0.y);
            z32[l] = cvtpk(ee0 * y0, ee1 * y1);            // z = ee_t o y_t ; ONE write
            float R0 = 0, R1 = 0, R2 = 0, R3 = 0, S0 = 0, S1 = 0, S2 = 0, S3 = 0;
            const uint4a* zw = (const uint4a*)z32;
            #pragma unroll
            for (int q = 0; q < 16; ++q) {
                const uint4 w = zw[q];                     // ds_read_b128 broadcast
                R0 = dot2b(w.x, RA[4 * q + 0], R0);  S0 = dot2b(w.x, RB[4 * q + 0], S0);
                R1 = dot2b(w.y, RA[4 * q + 1], R1);  S1 = dot2b(w.y, RB[4 * q + 1], S1);
                R2 = dot2b(w.z, RA[4 * q + 2], R2);  S2 = dot2b(w.z, RB[4 * q + 2], S2);
                R3 = dot2b(w.w, RA[4 * q + 3], R3);  S3 = dot2b(w.w, RB[4 * q + 3], S3);
            }
            const float rR = (R0 + R1) + (R2 + R3);
            const float rS = (S0 + S1) + (S2 + S3);
            Maccb -= __logf(invb);
            y0 = rR * invb;                                // delayed normalizer, mirrored
            y1 = rS * invb;
            invb = __builtin_amdgcn_rcpf(readlane0(rR));
            p0 = p1; p1 = p2; p2 = p3; p3 = pn;
        }
        #undef EIDXB
        meetY[c0] = y0; meetY[c1] = y1;
        if (l == 0) maccSh[1] = Maccb;
    } else {
        // ---- score: Viterbi-path gathers, concurrent with the recurrences ----
        float local = 0.f;
        for (int t = l; t < len; t += 64) {
            int tgt = target[t * B_SZ + b];
            float v = emit[(size_t)t * (B_SZ * N_ST) + b * N_ST + tgt];
            if (t > 0) v += trans[target[(t - 1) * B_SZ + b] * N_ST + tgt];
            local += v;
        }
        if (l == 0) {
            local += strans[target[b]];
            local += etrans[target[(len - 1) * B_SZ + b]];
        }
        #pragma unroll
        for (int off = 1; off < 64; off <<= 1) local += __shfl_xor(local, off);
        if (l == 0) score_out[b] = local;
    }

    // ---- meet: logZ = MaccF + MaccB + log( sum_j a_m[j] * y_m[j] ) ----
    __syncthreads();
    if (wid < 2) {
        float v = meetA[tid] * meetY[tid];
        #pragma unroll
        for (int off = 1; off < 64; off <<= 1) v += __shfl_xor(v, off);
        if (l == 0) red2[wid] = v;
    }
    __syncthreads();
    if (tid == 0) logZ_out[b] = maccSh[0] + maccSh[1] + __logf(red2[0] + red2[1]);

    // ---- last-block-done final reduce (replaces finalize kernel) ----
    __threadfence();                                        // release our logZ/score
    if (tid == 0) lastFlag = ((int)atomicAdd(done_cnt, 1u) == B_SZ - 1);
    __syncthreads();
    if (lastFlag) {
        __threadfence();                                    // acquire others' writes
        if (wid == 0) {                                     // 64 lanes x 4 batches, fixed order
            float v = 0.f;
            #pragma unroll
            for (int i = 0; i < 4; ++i) {
                const int idx = l * 4 + i;
                const float lz = __hip_atomic_load(&logZ_out[idx],  __ATOMIC_RELAXED,
                                                   __HIP_MEMORY_SCOPE_AGENT);
                const float sc = __hip_atomic_load(&score_out[idx], __ATOMIC_RELAXED,
                                                   __HIP_MEMORY_SCOPE_AGENT);
                v += lz - sc;
            }
            #pragma unroll
            for (int off = 1; off < 64; off <<= 1) v += __shfl_xor(v, off);
            if (l == 0) out[0] = v / 256.0f;
        }
    }
}

extern "C" void kernel_launch(void* const* d_in, const int* in_sizes, int n_in,
                              void* d_out, int out_size, void* d_ws, size_t ws_size,
                              hipStream_t stream) {
    const float*         emit   = (const float*)d_in[0];
    const int*           target = (const int*)d_in[1];
    const unsigned char* mask   = (const unsigned char*)d_in[2];
    const float*         trans  = (const float*)d_in[3];
    const float*         strans = (const float*)d_in[4];
    const float*         etrans = (const float*)d_in[5];

    float*  ws     = (float*)d_ws;
    float*  logZb  = ws;             // 256
    float*  scoreb = ws + 256;       // 256
    uint32* cnt    = (uint32*)(ws + 512);

    hipMemsetAsync(cnt, 0, sizeof(uint32), stream);   // reset done-counter每 launch (capture-safe)
    crf_fused_kernel<<<B_SZ, 192, 0, stream>>>(emit, mask, target, trans, strans, etrans,
                                               logZb, scoreb, cnt, (float*)d_out);
}

// Round 20
// 117.525 us; speedup vs baseline: 1.1613x; 1.1613x over previous
//
#include <hip/hip_runtime.h>

#define T_LEN 512
#define B_SZ  256
#define N_ST  128

#if defined(__has_builtin)
# if __has_builtin(__builtin_amdgcn_fdot2_f32_bf16)
#  define HAVE_DOT2 1
# endif
#endif
#ifndef HAVE_DOT2
# define HAVE_DOT2 0
#endif

typedef unsigned int uint32;
typedef __bf16 bf16x2 __attribute__((ext_vector_type(2)));
typedef float f2v __attribute__((ext_vector_type(2)));
typedef uint4 __attribute__((may_alias)) uint4a;   // alias-safe LDS vector read

__device__ __forceinline__ uint32 bf16rn(float f) {
    uint32 u = __builtin_bit_cast(uint32, f);
    u += 0x7fffu + ((u >> 16) & 1u);
    return u >> 16;
}
__device__ __forceinline__ uint32 pack2(float lo, float hi) {
    return bf16rn(lo) | (bf16rn(hi) << 16);
}
__device__ __forceinline__ uint32 cvtpk(float lo, float hi) {
    uint32 r;
    asm("v_cvt_pk_bf16_f32 %0, %1, %2" : "=v"(r) : "v"(lo), "v"(hi));
    return r;
}
__device__ __forceinline__ float readlane0(float v) {
    return __builtin_bit_cast(float, (uint32)__builtin_amdgcn_readlane(__builtin_bit_cast(int, v), 0));
}
__device__ __forceinline__ float dot2b(uint32 a, uint32 b, float c) {
#if HAVE_DOT2
    return __builtin_amdgcn_fdot2_f32_bf16(__builtin_bit_cast(bf16x2, a),
                                           __builtin_bit_cast(bf16x2, b), c, false);
#else
    float alo = __builtin_bit_cast(float, a << 16);
    float ahi = __builtin_bit_cast(float, a & 0xffff0000u);
    float blo = __builtin_bit_cast(float, b << 16);
    float bhi = __builtin_bit_cast(float, b & 0xffff0000u);
    return fmaf(ahi, bhi, fmaf(alo, blo, c));
#endif
}

// Per-wave length computation: 64 lanes x 8 mask entries for batch b.
// Each wave derives len independently -- no cross-wave sync needed.
__device__ __forceinline__ int wave_len(const unsigned char* __restrict__ mask_raw, int b, int l) {
    unsigned char b1 = mask_raw[1], b2 = mask_raw[2];
    int mode = (b1 != 0) ? 0 : ((b2 != 0) ? 2 : 1);
    int cnt = 0;
    if (mode == 0) {
        #pragma unroll
        for (int k = 0; k < 8; ++k) cnt += (mask_raw[(l * 8 + k) * B_SZ + b] != 0);
    } else if (mode == 1) {
        const int* mm = (const int*)mask_raw;
        #pragma unroll
        for (int k = 0; k < 8; ++k) cnt += (mm[(l * 8 + k) * B_SZ + b] != 0);
    } else {
        const float* mm = (const float*)mask_raw;
        #pragma unroll
        for (int k = 0; k < 8; ++k) cnt += (mm[(l * 8 + k) * B_SZ + b] != 0.0f);
    }
    #pragma unroll
    for (int off = 1; off < 64; off <<= 1) cnt += __shfl_xor(cnt, off);
    return cnt;
}

// ws layout (floats): [0..255] logZ_b ; [256..511] score_b

// Fully-fused CRF kernel: one block per batch, 3 waves.
//   wave0: forward recurrence  a_t = ee_t o (E^T a_{t-1}),  t = 1..m
//   wave1: backward recurrence y_{t-1} = E (ee_t o y_t),    t = len-1..m+1
//   wave2: Viterbi-path score (gathers), runs concurrently with the 256-step loops
// m = min(256, len-1). R18 verbatim (proven 117.6 us, absmax 0.0). R19's
// last-block-done variant regressed (-13 us: threadfence+atomic on every
// block's exit path beats the ~4 us launch-gap it saved) -- reverted.
__global__ void __attribute__((amdgpu_flat_work_group_size(192, 192), amdgpu_waves_per_eu(1, 1)))
crf_fused_kernel(
        const float* __restrict__ emit,
        const unsigned char* __restrict__ mask_raw,
        const int* __restrict__ target,
        const float* __restrict__ trans,
        const float* __restrict__ strans,
        const float* __restrict__ etrans,
        float* __restrict__ logZ_out,
        float* __restrict__ score_out) {
    const int b   = blockIdx.x;
    const int tid = threadIdx.x;      // 0..191
    const int wid = tid >> 6;         // 0 = fwd, 1 = bwd, 2 = score
    const int l   = tid & 63;
    const int c0  = 2 * l, c1 = 2 * l + 1;

    __shared__ alignas(16) uint32 a32[64];   // fwd a-vector, bf16x2 packed
    __shared__ alignas(16) uint32 z32[64];   // bwd ee*y vector, bf16x2 packed
    __shared__ float meetA[N_ST], meetY[N_ST];
    __shared__ float maccSh[2], red2[2];

    const int len = wave_len(mask_raw, b, l);    // per-wave, uniform within wave
    const int m = (len - 1 < 256) ? (len - 1) : 256;
    const float* eb = emit + (size_t)b * N_ST;
    const size_t TS2 = (size_t)B_SZ * N_ST / 2;
    const f2v* ebv = (const f2v*)eb;

    if (wid == 0) {
        // ---- forward: E columns c0, c1 packed over i-pairs ----
        uint32 EA[64], EB[64];
        #pragma unroll
        for (int p = 0; p < 64; ++p) {
            EA[p] = pack2(__expf(trans[(2 * p) * N_ST + c0]), __expf(trans[(2 * p + 1) * N_ST + c0]));
            EB[p] = pack2(__expf(trans[(2 * p) * N_ST + c1]), __expf(trans[(2 * p + 1) * N_ST + c1]));
        }
        float aA = __expf(strans[c0] + eb[c0]);
        float aB = __expf(strans[c1] + eb[c1]);
        a32[l] = pack2(aA, aB);
        float Macc = 0.f, inv = 1.0f;
        #define EIDX(T) ((size_t)(((T) <= m) ? (T) : m) * TS2 + l)
        f2v p0 = ebv[EIDX(1)];
        f2v p1 = ebv[EIDX(2)];
        f2v p2 = ebv[EIDX(3)];
        f2v p3 = ebv[EIDX(4)];
        for (int t = 1; t <= m; ++t) {
            const f2v pn = ebv[EIDX(t + 4)];               // prefetch, 4 iters ahead
            const float ee0 = __expf(p0.x), ee1 = __expf(p0.y);
            float A0 = 0, A1 = 0, A2 = 0, A3 = 0, B0 = 0, B1 = 0, B2 = 0, B3 = 0;
            const uint4a* aw = (const uint4a*)a32;
            #pragma unroll
            for (int q = 0; q < 16; ++q) {
                const uint4 w = aw[q];                     // ds_read_b128 broadcast
                A0 = dot2b(w.x, EA[4 * q + 0], A0);  B0 = dot2b(w.x, EB[4 * q + 0], B0);
                A1 = dot2b(w.y, EA[4 * q + 1], A1);  B1 = dot2b(w.y, EB[4 * q + 1], B1);
                A2 = dot2b(w.z, EA[4 * q + 2], A2);  B2 = dot2b(w.z, EB[4 * q + 2], B2);
                A3 = dot2b(w.w, EA[4 * q + 3], A3);  B3 = dot2b(w.w, EB[4 * q + 3], B3);
            }
            const float rA = (A0 + A1) + (A2 + A3);
            const float rB = (B0 + B1) + (B2 + B3);
            Macc -= __logf(inv);                           // bookkeeping (off write path)
            aA = ee0 * rA * inv;                           // delayed uniform normalizer
            aB = ee1 * rB * inv;
            a32[l] = cvtpk(aA, aB);                        // ONE ds_write_b32
            inv = __builtin_amdgcn_rcpf(readlane0(rA));    // scalar path, NOT DS pipe
            p0 = p1; p1 = p2; p2 = p3; p3 = pn;
        }
        #undef EIDX
        meetA[c0] = aA; meetA[c1] = aB;
        if (l == 0) maccSh[0] = Macc;
    } else if (wid == 1) {
        // ---- backward: E rows c0, c1 packed over j-pairs ----
        uint32 RA[64], RB[64];
        #pragma unroll
        for (int p = 0; p < 64; ++p) {
            RA[p] = pack2(__expf(trans[c0 * N_ST + 2 * p]), __expf(trans[c0 * N_ST + 2 * p + 1]));
            RB[p] = pack2(__expf(trans[c1 * N_ST + 2 * p]), __expf(trans[c1 * N_ST + 2 * p + 1]));
        }
        float y0 = __expf(etrans[c0]);                     // y_{len-1} = exp(etrans)
        float y1 = __expf(etrans[c1]);
        float Maccb = 0.f, invb = 1.0f;
        const int t0 = len - 1;
        #define EIDXB(T) ((size_t)(((T) > m) ? (T) : (m + 1)) * TS2 + l)
        f2v p0 = ebv[EIDXB(t0)];
        f2v p1 = ebv[EIDXB(t0 - 1)];
        f2v p2 = ebv[EIDXB(t0 - 2)];
        f2v p3 = ebv[EIDXB(t0 - 3)];
        for (int t = t0; t > m; --t) {
            const f2v pn = ebv[EIDXB(t - 4)];              // prefetch, 4 iters ahead
            const float ee0 = __expf(p0.x), ee1 = __expf(p0.y);
            z32[l] = cvtpk(ee0 * y0, ee1 * y1);            // z = ee_t o y_t ; ONE write
            float R0 = 0, R1 = 0, R2 = 0, R3 = 0, S0 = 0, S1 = 0, S2 = 0, S3 = 0;
            const uint4a* zw = (const uint4a*)z32;
            #pragma unroll
            for (int q = 0; q < 16; ++q) {
                const uint4 w = zw[q];                     // ds_read_b128 broadcast
                R0 = dot2b(w.x, RA[4 * q + 0], R0);  S0 = dot2b(w.x, RB[4 * q + 0], S0);
                R1 = dot2b(w.y, RA[4 * q + 1], R1);  S1 = dot2b(w.y, RB[4 * q + 1], S1);
                R2 = dot2b(w.z, RA[4 * q + 2], R2);  S2 = dot2b(w.z, RB[4 * q + 2], S2);
                R3 = dot2b(w.w, RA[4 * q + 3], R3);  S3 = dot2b(w.w, RB[4 * q + 3], S3);
            }
            const float rR = (R0 + R1) + (R2 + R3);
            const float rS = (S0 + S1) + (S2 + S3);
            Maccb -= __logf(invb);
            y0 = rR * invb;                                // delayed normalizer, mirrored
            y1 = rS * invb;
            invb = __builtin_amdgcn_rcpf(readlane0(rR));
            p0 = p1; p1 = p2; p2 = p3; p3 = pn;
        }
        #undef EIDXB
        meetY[c0] = y0; meetY[c1] = y1;
        if (l == 0) maccSh[1] = Maccb;
    } else {
        // ---- score: Viterbi-path gathers, concurrent with the recurrences ----
        float local = 0.f;
        for (int t = l; t < len; t += 64) {
            int tgt = target[t * B_SZ + b];
            float v = emit[(size_t)t * (B_SZ * N_ST) + b * N_ST + tgt];
            if (t > 0) v += trans[target[(t - 1) * B_SZ + b] * N_ST + tgt];
            local += v;
        }
        if (l == 0) {
            local += strans[target[b]];
            local += etrans[target[(len - 1) * B_SZ + b]];
        }
        #pragma unroll
        for (int off = 1; off < 64; off <<= 1) local += __shfl_xor(local, off);
        if (l == 0) score_out[b] = local;
    }

    // ---- meet: logZ = MaccF + MaccB + log( sum_j a_m[j] * y_m[j] ) ----
    __syncthreads();
    if (wid < 2) {
        float v = meetA[tid] * meetY[tid];
        #pragma unroll
        for (int off = 1; off < 64; off <<= 1) v += __shfl_xor(v, off);
        if (l == 0) red2[wid] = v;
    }
    __syncthreads();
    if (tid == 0) logZ_out[b] = maccSh[0] + maccSh[1] + __logf(red2[0] + red2[1]);
}

__global__ __launch_bounds__(256) void finalize_kernel(
        const float* __restrict__ logZ,
        const float* __restrict__ score,
        float* __restrict__ out) {
    int tid = threadIdx.x;  // 256
    float v = logZ[tid] - score[tid];
    #pragma unroll
    for (int off = 1; off < 64; off <<= 1) v += __shfl_xor(v, off);
    __shared__ float p[4];
    if ((tid & 63) == 0) p[tid >> 6] = v;
    __syncthreads();
    if (tid == 0) out[0] = (p[0] + p[1] + p[2] + p[3]) / 256.0f;
}

extern "C" void kernel_launch(void* const* d_in, const int* in_sizes, int n_in,
                              void* d_out, int out_size, void* d_ws, size_t ws_size,
                              hipStream_t stream) {
    const float*         emit   = (const float*)d_in[0];
    const int*           target = (const int*)d_in[1];
    const unsigned char* mask   = (const unsigned char*)d_in[2];
    const float*         trans  = (const float*)d_in[3];
    const float*         strans = (const float*)d_in[4];
    const float*         etrans = (const float*)d_in[5];

    float* ws     = (float*)d_ws;
    float* logZb  = ws;            // 256
    float* scoreb = ws + 256;      // 256

    crf_fused_kernel<<<B_SZ, 192, 0, stream>>>(emit, mask, target, trans, strans, etrans,
                                               logZb, scoreb);
    finalize_kernel<<<1, 256, 0, stream>>>(logZb, scoreb, (float*)d_out);
}